// Round 1
// baseline (244.596 us; speedup 1.0000x reference)
//
#include <hip/hip_runtime.h>
#include <math.h>

// Problem constants (from reference): L,B,T,H,K,R = 2,32,2048,512,64,7
#define L_ 2
#define B_ 32
#define T_ 2048
#define H_ 512
#define K_ 64
#define R_ 7
#define TT 64   // t-tile per block in energy kernel (4 waves x 16 t)

// ---------------------------------------------------------------------------
// tanh(x) = 1 - 2/(exp(2x)+1)  -- stable at both ends (inf -> 1, 0 -> -1),
// 1 v_exp + 1 v_rcp + 3 VALU. Error ~1e-7 abs, far below softmax tolerance.
__device__ __forceinline__ float tanh_fast(float x) {
    float e = __expf(2.0f * x);
    return 1.0f - 2.0f * __builtin_amdgcn_rcpf(e + 1.0f);
}

// ---------------------------------------------------------------------------
// ha[b,h] = sum_j mean_l(hidden[l,b,j]) * hp_w[h,j] + hp_b[h]
// grid (2, 8): x = h-half (256 h), y = group of 4 b. 256 threads, 1 h each.
__global__ void prep_ha(const float* __restrict__ hidden,
                        const float* __restrict__ hp_w,
                        const float* __restrict__ hp_b,
                        float* __restrict__ ha) {
    __shared__ float hm[4][H_];
    const int b0 = blockIdx.y * 4;
    const int h0 = blockIdx.x * 256;
    const int tid = threadIdx.x;
    for (int i = tid; i < 4 * H_; i += 256) {
        int bb = i >> 9, j = i & (H_ - 1);
        hm[bb][j] = 0.5f * (hidden[(0 * B_ + b0 + bb) * H_ + j] +
                            hidden[(1 * B_ + b0 + bb) * H_ + j]);
    }
    __syncthreads();
    const int h = h0 + tid;
    const float4* row = (const float4*)(hp_w + (size_t)h * H_);
    float acc0 = 0.f, acc1 = 0.f, acc2 = 0.f, acc3 = 0.f;
    for (int j4 = 0; j4 < H_ / 4; ++j4) {
        float4 w = row[j4];
        int j = j4 * 4;
        acc0 = fmaf(w.x, hm[0][j], fmaf(w.y, hm[0][j+1], fmaf(w.z, hm[0][j+2], fmaf(w.w, hm[0][j+3], acc0))));
        acc1 = fmaf(w.x, hm[1][j], fmaf(w.y, hm[1][j+1], fmaf(w.z, hm[1][j+2], fmaf(w.w, hm[1][j+3], acc1))));
        acc2 = fmaf(w.x, hm[2][j], fmaf(w.y, hm[2][j+1], fmaf(w.z, hm[2][j+2], fmaf(w.w, hm[2][j+3], acc2))));
        acc3 = fmaf(w.x, hm[3][j], fmaf(w.y, hm[3][j+1], fmaf(w.z, hm[3][j+2], fmaf(w.w, hm[3][j+3], acc3))));
    }
    float hb = hp_b[h];
    ha[(b0 + 0) * H_ + h] = acc0 + hb;
    ha[(b0 + 1) * H_ + h] = acc1 + hb;
    ha[(b0 + 2) * H_ + h] = acc2 + hb;
    ha[(b0 + 3) * H_ + h] = acc3 + hb;
}

// ---------------------------------------------------------------------------
// Fold conv kernel into the K-projection:
//   w2t[r,h] = sum_k pa_w[h,k] * conv_w[k,0,r]
//   c2[h]    = sum_k pa_w[h,k] * conv_b[k] + pa_b[h]
// grid 2 x 256 threads, one h per thread.
__global__ void prep_w2(const float* __restrict__ pa_w,
                        const float* __restrict__ pa_b,
                        const float* __restrict__ conv_w,
                        const float* __restrict__ conv_b,
                        float* __restrict__ w2t,
                        float* __restrict__ c2) {
    const int h = blockIdx.x * 256 + threadIdx.x;
    float wr[R_];
#pragma unroll
    for (int r = 0; r < R_; ++r) wr[r] = 0.f;
    float cb = 0.f;
    for (int k = 0; k < K_; ++k) {
        float pw = pa_w[h * K_ + k];
        cb = fmaf(pw, conv_b[k], cb);
#pragma unroll
        for (int r = 0; r < R_; ++r) wr[r] = fmaf(pw, conv_w[k * R_ + r], wr[r]);
    }
#pragma unroll
    for (int r = 0; r < R_; ++r) w2t[r * H_ + h] = wr[r];
    c2[h] = cb + pa_b[h];
}

// ---------------------------------------------------------------------------
// energy[b,t] = out_b + sum_h out_w[h] * tanh(enc[t,b,h] + ha[b,h] + c2[h]
//                                             + sum_r w2t[r,h]*pa[b,t+r-3])
// One wave per t. Lane l owns h in {4l..4l+3} and {256+4l..256+4l+3}:
// two coalesced float4 loads (1 KiB/wave-instr). Early-exit t >= enc_len[b]
// (those energies are masked to 0 downstream -> never read enc there).
__global__ __launch_bounds__(256, 4) void energy_kernel(
    const float* __restrict__ enc,       // (T,B,H)
    const float* __restrict__ prev_att,  // (B,T)
    const int*   __restrict__ enc_len,   // (B)
    const float* __restrict__ ha,        // (B,H)
    const float* __restrict__ w2t,       // (R,H)
    const float* __restrict__ c2,        // (H)
    const float* __restrict__ out_w,     // (H)
    const float* __restrict__ out_b,     // (1)
    float* __restrict__ energy)          // (B,T)  [aliases d_out]
{
    const int b  = blockIdx.y;
    const int t0 = blockIdx.x * TT;
    const int len = enc_len[b];
    if (t0 >= len) return;              // block-uniform: whole tile masked

    const int tid  = threadIdx.x;
    const int lane = tid & 63;
    const int wave = tid >> 6;

    __shared__ float pa_s[TT + 6];      // prev_att window [t0-3, t0+TT+3)
    for (int i = tid; i < TT + 6; i += 256) {
        int t = t0 - 3 + i;
        pa_s[i] = (t >= 0 && t < T_) ? prev_att[b * T_ + t] : 0.0f;
    }
    __syncthreads();

    // Per-lane constants (all coalesced float4 loads, L2-resident)
    const float4* haq = (const float4*)(ha + b * H_);
    const float4* c2q = (const float4*)c2;
    const float4* owq = (const float4*)out_w;
    float4 hacA = haq[lane];
    float4 hacB = haq[64 + lane];
    {
        float4 cA = c2q[lane], cB = c2q[64 + lane];
        hacA.x += cA.x; hacA.y += cA.y; hacA.z += cA.z; hacA.w += cA.w;
        hacB.x += cB.x; hacB.y += cB.y; hacB.z += cB.z; hacB.w += cB.w;
    }
    const float4 owA = owq[lane], owB = owq[64 + lane];
    float4 w2A[R_], w2B[R_];
#pragma unroll
    for (int r = 0; r < R_; ++r) {
        const float4* wq = (const float4*)(w2t + r * H_);
        w2A[r] = wq[lane];
        w2B[r] = wq[64 + lane];
    }
    const float ob = out_b[0];

    int t = t0 + wave * (TT / 4);
    const int tend = min(t + TT / 4, len);
    for (; t < tend; ++t) {
        const float4* e4 = (const float4*)(enc + ((size_t)t * B_ + b) * H_);
        float4 eA = e4[lane];            // h = 4*lane
        float4 eB = e4[64 + lane];       // h = 256 + 4*lane
        const int ti = t - t0;
        float4 cA = hacA, cB = hacB;
#pragma unroll
        for (int r = 0; r < R_; ++r) {   // 7-tap folded conv (wave-uniform p)
            float p = pa_s[ti + r];
            cA.x = fmaf(w2A[r].x, p, cA.x);
            cA.y = fmaf(w2A[r].y, p, cA.y);
            cA.z = fmaf(w2A[r].z, p, cA.z);
            cA.w = fmaf(w2A[r].w, p, cA.w);
            cB.x = fmaf(w2B[r].x, p, cB.x);
            cB.y = fmaf(w2B[r].y, p, cB.y);
            cB.z = fmaf(w2B[r].z, p, cB.z);
            cB.w = fmaf(w2B[r].w, p, cB.w);
        }
        float acc;
        acc  = owA.x * tanh_fast(eA.x + cA.x);
        acc += owA.y * tanh_fast(eA.y + cA.y);
        acc += owA.z * tanh_fast(eA.z + cA.z);
        acc += owA.w * tanh_fast(eA.w + cA.w);
        acc += owB.x * tanh_fast(eB.x + cB.x);
        acc += owB.y * tanh_fast(eB.y + cB.y);
        acc += owB.z * tanh_fast(eB.z + cB.z);
        acc += owB.w * tanh_fast(eB.w + cB.w);
#pragma unroll
        for (int off = 32; off > 0; off >>= 1)
            acc += __shfl_xor(acc, off);
        if (lane == 0) energy[b * T_ + t] = acc + ob;
    }
}

// ---------------------------------------------------------------------------
// Masked softmax over t, in-place on d_out. One block per b, 8 t per thread.
// Masked-out entries (t >= len) read poison but never feed max/sum; they are
// written as 0 exactly like the reference's final where(mask, w, 0).
__global__ void softmax_kernel(float* __restrict__ energy_out,
                               const int* __restrict__ enc_len) {
    const int b   = blockIdx.x;
    const int tid = threadIdx.x;
    const int len = enc_len[b];
    __shared__ float sm[4];
    const int wave = tid >> 6, lane = tid & 63;

    float e[8];
    float m = -1e30f;
#pragma unroll
    for (int i = 0; i < 8; ++i) {
        int t = tid + i * 256;
        e[i] = energy_out[b * T_ + t];
        if (t < len) m = fmaxf(m, e[i]);
    }
#pragma unroll
    for (int off = 32; off > 0; off >>= 1)
        m = fmaxf(m, __shfl_xor(m, off));
    if (lane == 0) sm[wave] = m;
    __syncthreads();
    m = fmaxf(fmaxf(sm[0], sm[1]), fmaxf(sm[2], sm[3]));
    __syncthreads();

    float p[8];
    float s = 0.f;
#pragma unroll
    for (int i = 0; i < 8; ++i) {
        int t = tid + i * 256;
        p[i] = (t < len) ? __expf(e[i] - m) : 0.0f;
        s += p[i];
    }
#pragma unroll
    for (int off = 32; off > 0; off >>= 1)
        s += __shfl_xor(s, off);
    if (lane == 0) sm[wave] = s;
    __syncthreads();
    s = sm[0] + sm[1] + sm[2] + sm[3];
    const float inv = 1.0f / s;          // full-precision divide, once
#pragma unroll
    for (int i = 0; i < 8; ++i) {
        int t = tid + i * 256;
        energy_out[b * T_ + t] = p[i] * inv;
    }
}

// ---------------------------------------------------------------------------
extern "C" void kernel_launch(void* const* d_in, const int* in_sizes, int n_in,
                              void* d_out, int out_size, void* d_ws, size_t ws_size,
                              hipStream_t stream) {
    const float* hidden   = (const float*)d_in[0];   // (L,B,H)
    const float* enc      = (const float*)d_in[1];   // (T,B,H)
    const int*   enc_len  = (const int*)  d_in[2];   // (B)
    const float* prev_att = (const float*)d_in[3];   // (B,T)
    const float* conv_w   = (const float*)d_in[4];   // (K,1,R)
    const float* conv_b   = (const float*)d_in[5];   // (K)
    const float* hp_w     = (const float*)d_in[6];   // (H,H)
    const float* hp_b     = (const float*)d_in[7];   // (H)
    const float* pa_w     = (const float*)d_in[8];   // (H,K)
    const float* pa_b     = (const float*)d_in[9];   // (H)
    const float* out_w    = (const float*)d_in[10];  // (1,H)
    const float* out_b    = (const float*)d_in[11];  // (1)

    float* out = (float*)d_out;                      // (B,T,1) -> also energy buffer
    float* ws  = (float*)d_ws;
    float* ha  = ws;                                 // B*H    = 16384 f
    float* w2t = ha + B_ * H_;                       // R*H    =  3584 f
    float* c2  = w2t + R_ * H_;                      // H      =   512 f
    // total ws usage: 20480 floats = 80 KiB

    prep_ha<<<dim3(2, 8), 256, 0, stream>>>(hidden, hp_w, hp_b, ha);
    prep_w2<<<2, 256, 0, stream>>>(pa_w, pa_b, conv_w, conv_b, w2t, c2);
    energy_kernel<<<dim3(T_ / TT, B_), 256, 0, stream>>>(
        enc, prev_att, enc_len, ha, w2t, c2, out_w, out_b, out);
    softmax_kernel<<<B_, 256, 0, stream>>>(out, enc_len);
}

// Round 4
// 237.093 us; speedup vs baseline: 1.0316x; 1.0316x over previous
//
#include <hip/hip_runtime.h>
#include <math.h>

// Problem constants (from reference): L,B,T,H,K,R = 2,32,2048,512,64,7
#define L_ 2
#define B_ 32
#define T_ 2048
#define H_ 512
#define K_ 64
#define R_ 7
#define TT 32   // t-tile per block in energy kernel (4 waves x 8 t)

// ---------------------------------------------------------------------------
// tanh(x) = 1 - 2/(exp(2x)+1)  -- stable at both ends, 1 v_exp + 1 v_rcp.
__device__ __forceinline__ float tanh_fast(float x) {
    float e = __expf(2.0f * x);
    return 1.0f - 2.0f * __builtin_amdgcn_rcpf(e + 1.0f);
}

// ---------------------------------------------------------------------------
// Fused prep: blocks 0..15 compute ha[b,h]; blocks 16..17 compute w2t/c2.
//   ha[b,h]  = sum_j mean_l(hidden[l,b,j]) * hp_w[h,j] + hp_b[h]
//   w2t[r,h] = sum_k pa_w[h,k] * conv_w[k,0,r]      (conv folded into proj)
//   c2[h]    = sum_k pa_w[h,k] * conv_b[k] + pa_b[h]
__global__ void prep_fused(const float* __restrict__ hidden,
                           const float* __restrict__ hp_w,
                           const float* __restrict__ hp_b,
                           const float* __restrict__ pa_w,
                           const float* __restrict__ pa_b,
                           const float* __restrict__ conv_w,
                           const float* __restrict__ conv_b,
                           float* __restrict__ ha,
                           float* __restrict__ w2t,
                           float* __restrict__ c2) {
    const int tid = threadIdx.x;
    if (blockIdx.x >= 16) {
        // ---- w2/c2 part: one h per thread -------------------------------
        const int h = (blockIdx.x - 16) * 256 + tid;
        float wr[R_];
#pragma unroll
        for (int r = 0; r < R_; ++r) wr[r] = 0.f;
        float cb = 0.f;
        for (int k = 0; k < K_; ++k) {
            float pw = pa_w[h * K_ + k];
            cb = fmaf(pw, conv_b[k], cb);
#pragma unroll
            for (int r = 0; r < R_; ++r) wr[r] = fmaf(pw, conv_w[k * R_ + r], wr[r]);
        }
#pragma unroll
        for (int r = 0; r < R_; ++r) w2t[r * H_ + h] = wr[r];
        c2[h] = cb + pa_b[h];
        return;
    }
    // ---- ha part: 4 b x 256 h per block ---------------------------------
    __shared__ float hm[4][H_];
    const int b0 = (blockIdx.x >> 1) * 4;
    const int h0 = (blockIdx.x & 1) * 256;
    for (int i = tid; i < 4 * H_; i += 256) {
        int bb = i >> 9, j = i & (H_ - 1);
        hm[bb][j] = 0.5f * (hidden[(b0 + bb) * H_ + j] +
                            hidden[(B_ + b0 + bb) * H_ + j]);
    }
    __syncthreads();
    const int h = h0 + tid;
    const float4* row = (const float4*)(hp_w + (size_t)h * H_);
    const float4* m0q = (const float4*)hm[0];
    const float4* m1q = (const float4*)hm[1];
    const float4* m2q = (const float4*)hm[2];
    const float4* m3q = (const float4*)hm[3];
    float a0 = 0.f, a1 = 0.f, a2 = 0.f, a3 = 0.f;
    for (int j4 = 0; j4 < H_ / 4; ++j4) {
        float4 w  = row[j4];
        float4 m0 = m0q[j4], m1 = m1q[j4], m2 = m2q[j4], m3 = m3q[j4];
        a0 = fmaf(w.x, m0.x, fmaf(w.y, m0.y, fmaf(w.z, m0.z, fmaf(w.w, m0.w, a0))));
        a1 = fmaf(w.x, m1.x, fmaf(w.y, m1.y, fmaf(w.z, m1.z, fmaf(w.w, m1.w, a1))));
        a2 = fmaf(w.x, m2.x, fmaf(w.y, m2.y, fmaf(w.z, m2.z, fmaf(w.w, m2.w, a2))));
        a3 = fmaf(w.x, m3.x, fmaf(w.y, m3.y, fmaf(w.z, m3.z, fmaf(w.w, m3.w, a3))));
    }
    float hb = hp_b[h];
    ha[(b0 + 0) * H_ + h] = a0 + hb;
    ha[(b0 + 1) * H_ + h] = a1 + hb;
    ha[(b0 + 2) * H_ + h] = a2 + hb;
    ha[(b0 + 3) * H_ + h] = a3 + hb;
}

// ---------------------------------------------------------------------------
// energy[b,t] = out_b + sum_h out_w[h] * tanh(enc[t,b,h] + ha[b,h] + c2[h]
//                                             + sum_r w2t[r,h]*pa[b,t+r-3])
// One wave per t-iteration; lane l owns h in {4l..4l+3, 256+4l..256+4l+3}
// (two coalesced float4 loads = contiguous 2 KiB row per t). TT=32 tile:
// ~4 waves/SIMD over active tiles. Explicit t+1 prefetch breaks the
// load->tanh->reduce serial chain. Blocks fully beyond enc_len exit (their
// energies are masked to 0 downstream -> enc rows never read there).
__global__ __launch_bounds__(256, 4) void energy_kernel(
    const float* __restrict__ enc,       // (T,B,H)
    const float* __restrict__ prev_att,  // (B,T)
    const int*   __restrict__ enc_len,   // (B)
    const float* __restrict__ ha,        // (B,H)
    const float* __restrict__ w2t,       // (R,H)
    const float* __restrict__ c2,        // (H)
    const float* __restrict__ out_w,     // (H)
    const float* __restrict__ out_b,     // (1)
    float* __restrict__ energy)          // (B,T)  [aliases d_out]
{
    const int b  = blockIdx.y;
    const int t0 = blockIdx.x * TT;
    const int len = enc_len[b];
    if (t0 >= len) return;              // block-uniform: whole tile masked

    const int tid  = threadIdx.x;
    const int lane = tid & 63;
    const int wave = tid >> 6;

    __shared__ float pa_s[TT + 6];      // prev_att window [t0-3, t0+TT+3)
    for (int i = tid; i < TT + 6; i += 256) {
        int t = t0 - 3 + i;
        pa_s[i] = (t >= 0 && t < T_) ? prev_att[b * T_ + t] : 0.0f;
    }
    __syncthreads();

    // Per-lane constants (coalesced float4 loads, L2-resident)
    const float4* haq = (const float4*)(ha + b * H_);
    const float4* c2q = (const float4*)c2;
    const float4* owq = (const float4*)out_w;
    float4 hacA = haq[lane];
    float4 hacB = haq[64 + lane];
    {
        float4 cA = c2q[lane], cB = c2q[64 + lane];
        hacA.x += cA.x; hacA.y += cA.y; hacA.z += cA.z; hacA.w += cA.w;
        hacB.x += cB.x; hacB.y += cB.y; hacB.z += cB.z; hacB.w += cB.w;
    }
    const float4 owA = owq[lane], owB = owq[64 + lane];
    float4 w2A[R_], w2B[R_];
#pragma unroll
    for (int r = 0; r < R_; ++r) {
        const float4* wq = (const float4*)(w2t + r * H_);
        w2A[r] = wq[lane];
        w2B[r] = wq[64 + lane];
    }
    const float ob = out_b[0];

    int t = t0 + wave * (TT / 4);
    const int tend = min(t + TT / 4, len);
    if (t < tend) {
        const float4* e4 = (const float4*)(enc + ((size_t)t * B_ + b) * H_);
        float4 eA = e4[lane];            // h = 4*lane
        float4 eB = e4[64 + lane];       // h = 256 + 4*lane
        for (; t < tend; ++t) {
            // -- prefetch next t's row before the dependent tanh chain ----
            float4 nA = eA, nB = eB;
            if (t + 1 < tend) {
                const float4* n4 = (const float4*)(enc + ((size_t)(t + 1) * B_ + b) * H_);
                nA = n4[lane];
                nB = n4[64 + lane];
            }
            const int ti = t - t0;
            float4 cA = hacA, cB = hacB;
#pragma unroll
            for (int r = 0; r < R_; ++r) {   // 7-tap folded conv (uniform p)
                float p = pa_s[ti + r];
                cA.x = fmaf(w2A[r].x, p, cA.x);
                cA.y = fmaf(w2A[r].y, p, cA.y);
                cA.z = fmaf(w2A[r].z, p, cA.z);
                cA.w = fmaf(w2A[r].w, p, cA.w);
                cB.x = fmaf(w2B[r].x, p, cB.x);
                cB.y = fmaf(w2B[r].y, p, cB.y);
                cB.z = fmaf(w2B[r].z, p, cB.z);
                cB.w = fmaf(w2B[r].w, p, cB.w);
            }
            float acc;
            acc  = owA.x * tanh_fast(eA.x + cA.x);
            acc += owA.y * tanh_fast(eA.y + cA.y);
            acc += owA.z * tanh_fast(eA.z + cA.z);
            acc += owA.w * tanh_fast(eA.w + cA.w);
            acc += owB.x * tanh_fast(eB.x + cB.x);
            acc += owB.y * tanh_fast(eB.y + cB.y);
            acc += owB.z * tanh_fast(eB.z + cB.z);
            acc += owB.w * tanh_fast(eB.w + cB.w);
#pragma unroll
            for (int off = 32; off > 0; off >>= 1)
                acc += __shfl_xor(acc, off);
            if (lane == 0) energy[b * T_ + t] = acc + ob;
            eA = nA; eB = nB;
        }
    }
}

// ---------------------------------------------------------------------------
// Masked softmax over t, in-place on d_out. One block per b, 8 t per thread.
// Masked-out entries (t >= len) read poison but never feed max/sum; they are
// written as 0, matching the reference's final where(mask, w, 0).
__global__ void softmax_kernel(float* __restrict__ energy_out,
                               const int* __restrict__ enc_len) {
    const int b   = blockIdx.x;
    const int tid = threadIdx.x;
    const int len = enc_len[b];
    __shared__ float sm[4];
    const int wave = tid >> 6, lane = tid & 63;

    float e[8];
    float m = -1e30f;
#pragma unroll
    for (int i = 0; i < 8; ++i) {
        int t = tid + i * 256;
        e[i] = energy_out[b * T_ + t];
        if (t < len) m = fmaxf(m, e[i]);
    }
#pragma unroll
    for (int off = 32; off > 0; off >>= 1)
        m = fmaxf(m, __shfl_xor(m, off));
    if (lane == 0) sm[wave] = m;
    __syncthreads();
    m = fmaxf(fmaxf(sm[0], sm[1]), fmaxf(sm[2], sm[3]));
    __syncthreads();

    float p[8];
    float s = 0.f;
#pragma unroll
    for (int i = 0; i < 8; ++i) {
        int t = tid + i * 256;
        p[i] = (t < len) ? __expf(e[i] - m) : 0.0f;
        s += p[i];
    }
#pragma unroll
    for (int off = 32; off > 0; off >>= 1)
        s += __shfl_xor(s, off);
    if (lane == 0) sm[wave] = s;
    __syncthreads();
    s = sm[0] + sm[1] + sm[2] + sm[3];
    const float inv = 1.0f / s;
#pragma unroll
    for (int i = 0; i < 8; ++i) {
        int t = tid + i * 256;
        energy_out[b * T_ + t] = p[i] * inv;
    }
}

// ---------------------------------------------------------------------------
extern "C" void kernel_launch(void* const* d_in, const int* in_sizes, int n_in,
                              void* d_out, int out_size, void* d_ws, size_t ws_size,
                              hipStream_t stream) {
    const float* hidden   = (const float*)d_in[0];   // (L,B,H)
    const float* enc      = (const float*)d_in[1];   // (T,B,H)
    const int*   enc_len  = (const int*)  d_in[2];   // (B)
    const float* prev_att = (const float*)d_in[3];   // (B,T)
    const float* conv_w   = (const float*)d_in[4];   // (K,1,R)
    const float* conv_b   = (const float*)d_in[5];   // (K)
    const float* hp_w     = (const float*)d_in[6];   // (H,H)
    const float* hp_b     = (const float*)d_in[7];   // (H)
    const float* pa_w     = (const float*)d_in[8];   // (H,K)
    const float* pa_b     = (const float*)d_in[9];   // (H)
    const float* out_w    = (const float*)d_in[10];  // (1,H)
    const float* out_b    = (const float*)d_in[11];  // (1)

    float* out = (float*)d_out;                      // (B,T,1) -> energy buffer
    float* ws  = (float*)d_ws;
    float* ha  = ws;                                 // B*H    = 16384 f
    float* w2t = ha + B_ * H_;                       // R*H    =  3584 f
    float* c2  = w2t + R_ * H_;                      // H      =   512 f
    // total ws usage: 20480 floats = 80 KiB

    prep_fused<<<18, 256, 0, stream>>>(hidden, hp_w, hp_b, pa_w, pa_b,
                                       conv_w, conv_b, ha, w2t, c2);
    energy_kernel<<<dim3(T_ / TT, B_), 256, 0, stream>>>(
        enc, prev_att, enc_len, ha, w2t, c2, out_w, out_b, out);
    softmax_kernel<<<B_, 256, 0, stream>>>(out, enc_len);
}